// Round 5
// baseline (220.016 us; speedup 1.0000x reference)
//
#include <hip/hip_runtime.h>
#include <hip/hip_bf16.h>
#include <cstdint>
#include <cstddef>

#define S_LEN   2048
#define BATCH   4
#define NHEAD   16
#define HDIM    64
#define DMODEL  1024
#define WIN     256
#define PQ      72   // padded LDS stride (144B = 36 banks -> 2-way, free)

typedef __bf16 bf16x8 __attribute__((ext_vector_type(8)));
typedef float f32x4 __attribute__((ext_vector_type(4)));
typedef unsigned short u16x4 __attribute__((ext_vector_type(4)));
typedef unsigned short u16x8 __attribute__((ext_vector_type(8)));

__device__ __forceinline__ unsigned short f2bf(float x) {
  union { float f; unsigned u; } c; c.f = x;
  unsigned r = (c.u + 0x7fffu + ((c.u >> 16) & 1u)) >> 16;
  return (unsigned short)r;
}

__device__ __forceinline__ void gld_lds16(const void* g, void* l) {
  __builtin_amdgcn_global_load_lds(
      (__attribute__((address_space(1))) void*)g,
      (__attribute__((address_space(3))) void*)l, 16, 0, 0);
}

// ---------------- fp32 -> bf16 conversion (hs + 4 weights) ----------------
__global__ __launch_bounds__(256) void convert_kernel(
    const float* __restrict__ s0, const float* __restrict__ s1,
    const float* __restrict__ s2, const float* __restrict__ s3,
    const float* __restrict__ s4,
    unsigned short* __restrict__ d0, unsigned short* __restrict__ d1,
    unsigned short* __restrict__ d2, unsigned short* __restrict__ d3,
    unsigned short* __restrict__ d4) {
  const int z = blockIdx.y;
  const float* s; unsigned short* d; long n;
  if      (z == 0) { s = s0; d = d0; n = (long)8192 * 1024; }
  else if (z == 1) { s = s1; d = d1; n = (long)1024 * 1024; }
  else if (z == 2) { s = s2; d = d2; n = (long)1024 * 1024; }
  else if (z == 3) { s = s3; d = d3; n = (long)1024 * 1024; }
  else             { s = s4; d = d4; n = (long)1024 * 1024; }
  const long base = ((long)blockIdx.x * 256 + threadIdx.x) * 16;
  if (base >= n) return;
#pragma unroll
  for (int i = 0; i < 4; ++i) {
    const float4 f = *(const float4*)(s + base + i * 4);
    u16x4 ov;
    ov.x = f2bf(f.x); ov.y = f2bf(f.y); ov.z = f2bf(f.z); ov.w = f2bf(f.w);
    *(u16x4*)(d + base + i * 4) = ov;
  }
}

// ======================================================================
// qkv GEMM core R5: C[M,N] = A[M,K] @ B[N,K]^T
// 256x256 tile, BK=64, 512 threads (8 waves 2Mx4N, per-wave 128x64,
// acc = 8x4 f32x4 = 128 VGPR). 2-region LDS double buffer (64KB/region,
// 128KB, 1 blk/CU).
// WHY 256^2: LDS-bandwidth balance. Fragment traffic per tile per CU is
// 8 waves x (Wm+Wn) x 128B; FLOP is BM*BN*64*2. At 128x256/64x64-waves
// the LDS pipe needs ~2120cy vs 1030cy of MFMA (2x oversubscribed ->
// MfmaUtil capped ~49%, measured 34%). At 256^2/128x64-waves both are
// ~2050cy -> balanced (m201's geometry, 62% there).
// Schedule (m201 pattern): stage ALL 8 gld_lds for tile t+1 at tile top
// (region r^1 provably free: its last readers completed before the
// boundary barrier we just crossed); 4 phases of {ds_reads -> s_barrier
// (arrive with reads in flight; barrier wait overlaps read latency) ->
// sched_barrier(0) pin -> setprio(1) + 16 MFMA}; B-frags read once per
// k-slice, reused across both mi-halves. Boundary vmcnt(0) is free:
// the 8 loads had ~4 phases (~2500cy >> 900cy HBM) to land.
// ======================================================================
template <int MODE>
__device__ __forceinline__ void gemm_pipe_core(
    const unsigned short* __restrict__ A, const unsigned short* __restrict__ B,
    void* __restrict__ C, const float* __restrict__ bias,
    int M, int N, int K, unsigned short* __restrict__ ls) {
  const int m0 = blockIdx.x * 256;
  const int n0 = blockIdx.y * 256;
  const int tid  = threadIdx.x;
  const int lane = tid & 63;
  const int wid  = tid >> 6;
  const int quad = lane >> 4, l16 = lane & 15;
  const int wm = wid >> 2, wn = wid & 3;   // 2x4 wave grid; wave tile 128x64

  const int REG = 32768;                   // elems/region: A 16384 + B 16384

  // staging: row = (tid>>3) + 64q (q=0..3), chunk = tid&7
  // swz(row) = (row>>1)&7 = (tid>>4)&7 for all q (64q even, 32q = 0 mod 8)
  const int srow   = tid >> 3;
  const int schunk = tid & 7;
  const int scol   = ((schunk ^ ((tid >> 4) & 7)) << 3);
  const int swz_r  = (l16 >> 1) & 7;       // read-side swizzle (row>>1)&7

  f32x4 acc[8][4];
#pragma unroll
  for (int i = 0; i < 8; ++i)
#pragma unroll
    for (int j = 0; j < 4; ++j) acc[i][j] = f32x4{0.f, 0.f, 0.f, 0.f};

  const int NT = K >> 6;

  // ---- prologue: stage tile 0 into region 0 (8 loads) ----
#pragma unroll
  for (int q = 0; q < 4; ++q) {
    const int row = srow + 64 * q;
    gld_lds16(A + (size_t)(m0 + row) * K + scol, ls + row * 64 + schunk * 8);
  }
#pragma unroll
  for (int q = 0; q < 4; ++q) {
    const int row = srow + 64 * q;
    gld_lds16(B + (size_t)(n0 + row) * K + scol,
              ls + 16384 + row * 64 + schunk * 8);
  }
  asm volatile("s_waitcnt vmcnt(0)" ::: "memory");
  __builtin_amdgcn_s_barrier();
  __builtin_amdgcn_sched_barrier(0);

  for (int t = 0; t < NT; ++t) {
    const unsigned short* la = ls + (t & 1) * REG;
    const unsigned short* lb = la + 16384;
    unsigned short* da = ls + ((t + 1) & 1) * REG;
    const bool doStage = (t + 1) < NT;
    const int k0s = (t + 1) << 6;

    // stage tile t+1 (region r^1 free: last read before boundary barrier)
    if (doStage) {
#pragma unroll
      for (int q = 0; q < 4; ++q) {
        const int row = srow + 64 * q;
        gld_lds16(A + (size_t)(m0 + row) * K + k0s + scol,
                  da + row * 64 + schunk * 8);
      }
#pragma unroll
      for (int q = 0; q < 4; ++q) {
        const int row = srow + 64 * q;
        gld_lds16(B + (size_t)(n0 + row) * K + k0s + scol,
                  da + 16384 + row * 64 + schunk * 8);
      }
    }

#pragma unroll
    for (int s2 = 0; s2 < 2; ++s2) {
      const int rc = ((s2 * 4 + quad) ^ swz_r) << 3;
      bf16x8 bfr[4], afl[4];
      // ---- phase A: read B-frags + A-frags (mi 0..3) ----
#pragma unroll
      for (int ni = 0; ni < 4; ++ni)
        bfr[ni] = *(const bf16x8*)(lb + (wn * 64 + ni * 16 + l16) * 64 + rc);
#pragma unroll
      for (int mi = 0; mi < 4; ++mi)
        afl[mi] = *(const bf16x8*)(la + (wm * 128 + mi * 16 + l16) * 64 + rc);
      __builtin_amdgcn_s_barrier();          // arrive with reads in flight
      __builtin_amdgcn_sched_barrier(0);
      __builtin_amdgcn_s_setprio(1);
#pragma unroll
      for (int mi = 0; mi < 4; ++mi)
#pragma unroll
        for (int ni = 0; ni < 4; ++ni)
          acc[mi][ni] = __builtin_amdgcn_mfma_f32_16x16x32_bf16(
              afl[mi], bfr[ni], acc[mi][ni], 0, 0, 0);
      __builtin_amdgcn_s_setprio(0);

      // ---- phase B: read A-frags (mi 4..7); B-frags reused ----
#pragma unroll
      for (int mi = 0; mi < 4; ++mi)
        afl[mi] = *(const bf16x8*)(la + (wm * 128 + (mi + 4) * 16 + l16) * 64 + rc);
      __builtin_amdgcn_s_barrier();
      __builtin_amdgcn_sched_barrier(0);
      __builtin_amdgcn_s_setprio(1);
#pragma unroll
      for (int mi = 0; mi < 4; ++mi)
#pragma unroll
        for (int ni = 0; ni < 4; ++ni)
          acc[mi + 4][ni] = __builtin_amdgcn_mfma_f32_16x16x32_bf16(
              afl[mi], bfr[ni], acc[mi + 4][ni], 0, 0, 0);
      __builtin_amdgcn_s_setprio(0);
    }

    // boundary: land tile t+1 (free: issued ~4 phases ago), recycle region
    if (doStage) {
      asm volatile("s_waitcnt vmcnt(0)" ::: "memory");
      __builtin_amdgcn_s_barrier();
      __builtin_amdgcn_sched_barrier(0);
    }
  }

  // epilogue: C/D layout col=lane&15, row=quad*4+reg
#pragma unroll
  for (int mi = 0; mi < 8; ++mi) {
    if (MODE == 2) {
      // transposed V write: m = token -> (b, s); n = feature -> (h, d)
      const int mB = m0 + wm * 128 + mi * 16 + quad * 4;   // r=0..3 -> s..s+3
      const int bq = mB >> 11, s = mB & 2047;
#pragma unroll
      for (int ni = 0; ni < 4; ++ni) {
        const int n = n0 + wn * 64 + ni * 16 + l16;
        u16x4 w;
        w[0] = f2bf(acc[mi][ni][0]); w[1] = f2bf(acc[mi][ni][1]);
        w[2] = f2bf(acc[mi][ni][2]); w[3] = f2bf(acc[mi][ni][3]);
        *(u16x4*)((unsigned short*)C +
                  (((size_t)((bq << 4) | (n >> 6)) * 64 + (n & 63)) << 11) + s) = w;
      }
    } else {
#pragma unroll
      for (int r = 0; r < 4; ++r) {
        const int m = m0 + wm * 128 + mi * 16 + quad * 4 + r;
#pragma unroll
        for (int ni = 0; ni < 4; ++ni) {
          const int n = n0 + wn * 64 + ni * 16 + l16;
          const float vv = acc[mi][ni][r];
          if (MODE == 0) {
            ((unsigned short*)C)[(size_t)m * N + n] = f2bf(vv);
          } else {
            ((float*)C)[(size_t)m * N + n] = vv + bias[n];
          }
        }
      }
    }
  }
}

// fused q/k/v projection; z==2 (V) writes transposed into vt[bh][d][s]
__global__ __launch_bounds__(512, 2) void gemm_qkv_kernel(
    const unsigned short* __restrict__ A,
    const unsigned short* __restrict__ B0, const unsigned short* __restrict__ B1,
    const unsigned short* __restrict__ B2,
    unsigned short* __restrict__ C0, unsigned short* __restrict__ C1,
    unsigned short* __restrict__ Cv, int M, int N, int K) {
  __shared__ unsigned short ls[2 * 32768];   // 128 KB
  if (blockIdx.z == 2) {
    gemm_pipe_core<2>(A, B2, Cv, nullptr, M, N, K, ls);
  } else {
    const unsigned short* B = blockIdx.z == 0 ? B0 : B1;
    unsigned short*       C = blockIdx.z == 0 ? C0 : C1;
    gemm_pipe_core<0>(A, B, C, nullptr, M, N, K, ls);
  }
}

// ---------------- old proven 128^2 GEMM core (control, gemm_out) ---------
template <int MODE>
__device__ __forceinline__ void gemm_bt_core(
    const unsigned short* __restrict__ A, const unsigned short* __restrict__ B,
    void* __restrict__ C, const float* __restrict__ bias,
    int M, int N, int K,
    unsigned short* __restrict__ lsA, unsigned short* __restrict__ lsB) {
  const int m0 = blockIdx.x * 128;
  const int n0 = blockIdx.y * 128;
  const int tid  = threadIdx.x;
  const int wave = tid >> 6, lane = tid & 63;
  const int quad = lane >> 4, l16 = lane & 15;
  const int wm = wave >> 1, wn = wave & 1;   // 2x2 wave grid over 128x128

  f32x4 acc[4][4];
#pragma unroll
  for (int i = 0; i < 4; ++i)
#pragma unroll
    for (int j = 0; j < 4; ++j) acc[i][j] = f32x4{0.f, 0.f, 0.f, 0.f};

  const int trow   = tid >> 3;
  const int tchunk = tid & 7;
  const int swz_w  = (trow >> 1) & 7;
  const int scol   = ((tchunk ^ swz_w) << 3);
  const int swz_r  = (l16 >> 1) & 7;

  for (int k0 = 0; k0 < K; k0 += 64) {
    __syncthreads();
#pragma unroll
    for (int c = 0; c < 4; ++c) {
      const int row  = trow + 32 * c;
      const int flat = row * 64 + tchunk * 8;
      gld_lds16(A + (size_t)(m0 + row) * K + k0 + scol, lsA + flat);
      gld_lds16(B + (size_t)(n0 + row) * K + k0 + scol, lsB + flat);
    }
    __syncthreads();

#pragma unroll
    for (int s2 = 0; s2 < 2; ++s2) {
      bf16x8 af[4], bfr[4];
#pragma unroll
      for (int mi = 0; mi < 4; ++mi)
        af[mi] = *(const bf16x8*)(lsA + (wm * 64 + mi * 16 + l16) * 64 +
                                  (((s2 * 4 + quad) ^ swz_r) << 3));
#pragma unroll
      for (int ni = 0; ni < 4; ++ni)
        bfr[ni] = *(const bf16x8*)(lsB + (wn * 64 + ni * 16 + l16) * 64 +
                                   (((s2 * 4 + quad) ^ swz_r) << 3));
#pragma unroll
      for (int mi = 0; mi < 4; ++mi)
#pragma unroll
        for (int ni = 0; ni < 4; ++ni)
          acc[mi][ni] = __builtin_amdgcn_mfma_f32_16x16x32_bf16(
              af[mi], bfr[ni], acc[mi][ni], 0, 0, 0);
    }
  }

#pragma unroll
  for (int mi = 0; mi < 4; ++mi) {
#pragma unroll
    for (int r = 0; r < 4; ++r) {
      const int m = m0 + wm * 64 + mi * 16 + quad * 4 + r;
#pragma unroll
      for (int ni = 0; ni < 4; ++ni) {
        const int n = n0 + wn * 64 + ni * 16 + l16;
        const float vv = acc[mi][ni][r];
        if (MODE == 0) {
          ((unsigned short*)C)[(size_t)m * N + n] = f2bf(vv);
        } else {
          ((float*)C)[(size_t)m * N + n] = vv + bias[n];
        }
      }
    }
  }
}

__global__ __launch_bounds__(256) void gemm_out_kernel(
    const unsigned short* __restrict__ A, const unsigned short* __restrict__ B,
    float* __restrict__ C, const float* __restrict__ bias, int M, int N, int K) {
  __shared__ unsigned short lsA[128 * 64];
  __shared__ unsigned short lsB[128 * 64];
  gemm_bt_core<1>(A, B, C, bias, M, N, K, lsA, lsB);
}

// ---------------- sliding-window flash attention, P-in-registers ----------
// (unchanged from R2: T14 async-STAGE split + T5 setprio + unsigned mask)
__global__ __launch_bounds__(256) void attn_kernel(
    const unsigned short* __restrict__ q, const unsigned short* __restrict__ k,
    const unsigned short* __restrict__ vt, unsigned short* __restrict__ ctx) {
  const int bh = blockIdx.y;
  const int b = bh >> 4, h = bh & 15;
  const int i0 = blockIdx.x * 128;
  const int tid  = threadIdx.x;
  const int wave = tid >> 6, lane = tid & 63;
  const int quad = lane >> 4, l16 = lane & 15;

  __shared__ unsigned short lsQ[128 * PQ];   // [query][dim]
  __shared__ unsigned short lsK[64 * PQ];    // [key][dim]
  __shared__ unsigned short lsVp[64 * PQ];   // [dim][kslot] sigma-permuted V^T

  { // stage Q: thread pair covers one row (128B contiguous per pair)
    const int r = tid >> 1, cb = (tid & 1) * 32;
    const unsigned short* src =
        q + ((size_t)(b * S_LEN + i0 + r) * DMODEL + h * HDIM + cb);
    *(u16x8*)(lsQ + r * PQ + cb)      = *(const u16x8*)src;
    *(u16x8*)(lsQ + r * PQ + cb + 8)  = *(const u16x8*)(src + 8);
    *(u16x8*)(lsQ + r * PQ + cb + 16) = *(const u16x8*)(src + 16);
    *(u16x8*)(lsQ + r * PQ + cb + 24) = *(const u16x8*)(src + 24);
  }

  // K/V staging geometry (persistent)
  const int rr = tid >> 2, cb = (tid & 3) * 16;
  const int jhi  = cb >> 4;                          // = tid&3
  const int vbase = (jhi >> 1) * 32 + (jhi & 1) * 4; // s2*32 + jh*4

  // earliest key needed by any query in [i0, i0+127] is i0-(WIN-1)
  const int jb0 = (i0 >= WIN) ? ((i0 - WIN + 1) >> 6) : 0;
  const int jb1 = (i0 + 127) >> 6;
  const int jbi = i0 >> 6;

  // prefetch registers for next j-block's K/V (T14 async-STAGE split)
  u16x8 pk0, pk1, pv0, pv1;
  {
    const int j0 = jb0 * 64;
    const unsigned short* ks =
        k + ((size_t)(b * S_LEN + j0 + rr) * DMODEL + h * HDIM + cb);
    pk0 = *(const u16x8*)ks;
    pk1 = *(const u16x8*)(ks + 8);
    const unsigned short* vs =
        vt + ((size_t)(bh * HDIM + rr) * S_LEN + j0 + cb);
    pv0 = *(const u16x8*)vs;
    pv1 = *(const u16x8*)(vs + 8);
  }

  __syncthreads();   // lsQ ready

  // Q B-fragments in registers for the whole j-loop: q = w*32 + t*16 + l16
  bf16x8 aq[2][2];
#pragma unroll
  for (int t = 0; t < 2; ++t)
#pragma unroll
    for (int s2 = 0; s2 < 2; ++s2)
      aq[t][s2] = *(const bf16x8*)(lsQ + (wave * 32 + t * 16 + l16) * PQ +
                                   s2 * 32 + quad * 8);

  float l_lane[2] = {0.f, 0.f};   // lane-local partial softmax denominators
  f32x4 o[2][4];                  // O: [t][d-tile], row=quad*4+r=q_lo, col=l16=d_lo
#pragma unroll
  for (int t = 0; t < 2; ++t)
#pragma unroll
    for (int nd = 0; nd < 4; ++nd) o[t][nd] = f32x4{0.f, 0.f, 0.f, 0.f};

  for (int jb = jb0; jb <= jb1; ++jb) {
    const int j0 = jb * 64;
    // fully-valid blocks for ALL 128 queries: j0+63 <= i0 and i0+127-j0 < WIN
    const bool needMask = !(jb == jbi - 1 || jb == jbi - 2);
    __syncthreads();   // all waves done reading lsK/lsVp of previous jb
    { // write prefetched regs: K row-major; V^T sigma-permuted to kslots
      *(u16x8*)(lsK + rr * PQ + cb)     = pk0;
      *(u16x8*)(lsK + rr * PQ + cb + 8) = pk1;
      u16x4 w0, w1, w2, w3;
      w0[0]=pv0[0]; w0[1]=pv0[1]; w0[2]=pv0[2]; w0[3]=pv0[3];
      w1[0]=pv0[4]; w1[1]=pv0[5]; w1[2]=pv0[6]; w1[3]=pv0[7];
      w2[0]=pv1[0]; w2[1]=pv1[1]; w2[2]=pv1[2]; w2[3]=pv1[3];
      w3[0]=pv1[4]; w3[1]=pv1[5]; w3[2]=pv1[6]; w3[3]=pv1[7];
      *(u16x4*)(lsVp + rr * PQ + vbase)      = w0;   // keys m=0..3
      *(u16x4*)(lsVp + rr * PQ + vbase + 8)  = w1;   // keys m=4..7
      *(u16x4*)(lsVp + rr * PQ + vbase + 16) = w2;   // keys m=8..11
      *(u16x4*)(lsVp + rr * PQ + vbase + 24) = w3;   // keys m=12..15
    }
    __syncthreads();

    if (jb < jb1) {   // issue next tile's loads; in flight under compute
      const int jn = j0 + 64;
      const unsigned short* ks =
          k + ((size_t)(b * S_LEN + jn + rr) * DMODEL + h * HDIM + cb);
      pk0 = *(const u16x8*)ks;
      pk1 = *(const u16x8*)(ks + 8);
      const unsigned short* vs =
          vt + ((size_t)(bh * HDIM + rr) * S_LEN + jn + cb);
      pv0 = *(const u16x8*)vs;
      pv1 = *(const u16x8*)(vs + 8);
    }

    // S^T = K @ Q^T : lane holds S[q = w*32+t*16+l16][j = ni*16+quad*4+r]
    f32x4 st[2][4];
#pragma unroll
    for (int t = 0; t < 2; ++t)
#pragma unroll
      for (int ni = 0; ni < 4; ++ni) st[t][ni] = f32x4{0.f, 0.f, 0.f, 0.f};
    __builtin_amdgcn_s_setprio(1);
#pragma unroll
    for (int s2 = 0; s2 < 2; ++s2) {
      bf16x8 bk[4];
#pragma unroll
      for (int ni = 0; ni < 4; ++ni)
        bk[ni] = *(const bf16x8*)(lsK + (ni * 16 + l16) * PQ + s2 * 32 + quad * 8);
#pragma unroll
      for (int t = 0; t < 2; ++t)
#pragma unroll
        for (int ni = 0; ni < 4; ++ni)
          st[t][ni] = __builtin_amdgcn_mfma_f32_16x16x32_bf16(
              bk[ni], aq[t][s2], st[t][ni], 0, 0, 0);
    }
    __builtin_amdgcn_s_setprio(0);

    bf16x8 ap[2][2];   // PV A-frags, packed via sigma
#pragma unroll
    for (int t = 0; t < 2; ++t) {
      const int iq = i0 + wave * 32 + t * 16 + l16;
      if (needMask) {
#pragma unroll
        for (int ni = 0; ni < 4; ++ni)
#pragma unroll
          for (int r = 0; r < 4; ++r) {
            const int j = j0 + ni * 16 + quad * 4 + r;
            const bool ok = ((unsigned)(iq - j) < (unsigned)WIN);
            const float p = ok ? __expf(fminf(st[t][ni][r], 80.f)) : 0.f;
            st[t][ni][r] = p;
            l_lane[t] += p;
          }
      } else {
#pragma unroll
        for (int ni = 0; ni < 4; ++ni)
#pragma unroll
          for (int r = 0; r < 4; ++r) {
            const float p = __expf(fminf(st[t][ni][r], 80.f));
            st[t][ni][r] = p;
            l_lane[t] += p;
          }
      }
      // sigma pack: ap[t][s2][idx] = P at (ni = s2*2 + idx>>2, r = idx&3)
#pragma unroll
      for (int s2 = 0; s2 < 2; ++s2) {
        bf16x8 a;
#pragma unroll
        for (int r = 0; r < 4; ++r) {
          union { unsigned short u; __bf16 h; } c0, c1;
          c0.u = f2bf(st[t][2 * s2][r]);
          c1.u = f2bf(st[t][2 * s2 + 1][r]);
          a[r]     = c0.h;
          a[4 + r] = c1.h;
        }
        ap[t][s2] = a;
      }
    }

    // O += P @ V  (B-frags shared across t)
    __builtin_amdgcn_s_setprio(1);
#pragma unroll
    for (int s2 = 0; s2 < 2; ++s2) {
      bf16x8 bv[4];
#pragma unroll
      for (int nd = 0; nd < 4; ++nd)
        bv[nd] = *(const bf16x8*)(lsVp + (nd * 16 + l16) * PQ + s2 * 32 + quad * 8);
#pragma unroll
      for (int t = 0; t < 2; ++t)
#pragma unroll
        for (int nd = 0; nd < 4; ++nd)
          o[t][nd] = __builtin_amdgcn_mfma_f32_16x16x32_bf16(
              ap[t][s2], bv[nd], o[t][nd], 0, 0, 0);
    }
    __builtin_amdgcn_s_setprio(0);
  }

  // epilogue: reduce l across quads once, then normalize + store
#pragma unroll
  for (int t = 0; t < 2; ++t) {
    float l = l_lane[t];
    l += __shfl_xor(l, 16, 64);
    l += __shfl_xor(l, 32, 64);
    const float invl = 1.f / l;
#pragma unroll
    for (int r = 0; r < 4; ++r) {
      const float inv = __shfl(invl, quad * 4 + r, 64);
      const int i = i0 + wave * 32 + t * 16 + quad * 4 + r;
#pragma unroll
      for (int nd = 0; nd < 4; ++nd)
        ctx[(size_t)(b * S_LEN + i) * DMODEL + h * HDIM + nd * 16 + l16] =
            f2bf(o[t][nd][r] * inv);
    }
  }
}

// --------------------------------------------------------------------------
extern "C" void kernel_launch(void* const* d_in, const int* in_sizes, int n_in,
                              void* d_out, int out_size, void* d_ws, size_t ws_size,
                              hipStream_t stream) {
  const float* hs = (const float*)d_in[0];
  const float* Wq = (const float*)d_in[1];
  const float* Wk = (const float*)d_in[2];
  const float* Wv = (const float*)d_in[3];
  const float* Wo = (const float*)d_in[4];
  const float* bo = (const float*)d_in[5];
  float* out = (float*)d_out;

  const size_t MD = (size_t)8192 * 1024;
  const size_t DD = (size_t)1024 * 1024;
  unsigned short* hsb  = (unsigned short*)d_ws;
  unsigned short* wqb  = hsb + MD;
  unsigned short* wkb  = wqb + DD;
  unsigned short* wvb  = wkb + DD;
  unsigned short* wob  = wvb + DD;
  unsigned short* qb   = wob + DD;
  unsigned short* kb   = qb + MD;
  unsigned short* vtb  = kb + MD;          // V^T [bh][d][s] (direct from GEMM)
  unsigned short* ctxb = vtb + MD;

  convert_kernel<<<dim3(2048, 5), 256, 0, stream>>>(hs, Wq, Wk, Wv, Wo,
                                                    hsb, wqb, wkb, wvb, wob);
  gemm_qkv_kernel<<<dim3(32, 4, 3), 512, 0, stream>>>(hsb, wqb, wkb, wvb,
                                                      qb, kb, vtb, 8192, 1024, 1024);
  attn_kernel<<<dim3(16, 64), 256, 0, stream>>>(qb, kb, vtb, ctxb);
  gemm_out_kernel<<<dim3(64, 8), 256, 0, stream>>>(ctxb, wob, out, bo,
                                                   8192, 1024, 1024);
}

// Round 6
// 196.911 us; speedup vs baseline: 1.1173x; 1.1173x over previous
//
#include <hip/hip_runtime.h>
#include <hip/hip_bf16.h>
#include <cstdint>
#include <cstddef>

#define S_LEN   2048
#define BATCH   4
#define NHEAD   16
#define HDIM    64
#define DMODEL  1024
#define WIN     256
#define PQ      72   // padded LDS stride (144B = 36 banks -> 2-way, free)

typedef __bf16 bf16x8 __attribute__((ext_vector_type(8)));
typedef float f32x4 __attribute__((ext_vector_type(4)));
typedef unsigned short u16x4 __attribute__((ext_vector_type(4)));
typedef unsigned short u16x8 __attribute__((ext_vector_type(8)));

__device__ __forceinline__ unsigned short f2bf(float x) {
  union { float f; unsigned u; } c; c.f = x;
  unsigned r = (c.u + 0x7fffu + ((c.u >> 16) & 1u)) >> 16;
  return (unsigned short)r;
}

// HW packed f32->bf16 (RNE), 1 instr for 2 values; replaces the 3-4 VALU
// manual RNE trick in hot paths. Compiler can't derive this from f2bf.
__device__ __forceinline__ unsigned cvt_pk_bf16(float lo, float hi) {
  unsigned r;
  asm("v_cvt_pk_bf16_f32 %0, %1, %2" : "=v"(r) : "v"(lo), "v"(hi));
  return r;
}

__device__ __forceinline__ void gld_lds16(const void* g, void* l) {
  __builtin_amdgcn_global_load_lds(
      (__attribute__((address_space(1))) void*)g,
      (__attribute__((address_space(3))) void*)l, 16, 0, 0);
}

// ---------------- fp32 -> bf16 conversion (hs + 4 weights) ----------------
// grid-stride: (512,5); z=0 loops 4x, z>0 half the blocks do 1 chunk.
__global__ __launch_bounds__(256) void convert_kernel(
    const float* __restrict__ s0, const float* __restrict__ s1,
    const float* __restrict__ s2, const float* __restrict__ s3,
    const float* __restrict__ s4,
    unsigned short* __restrict__ d0, unsigned short* __restrict__ d1,
    unsigned short* __restrict__ d2, unsigned short* __restrict__ d3,
    unsigned short* __restrict__ d4) {
  const int z = blockIdx.y;
  const float* s; unsigned short* d; long n;
  if      (z == 0) { s = s0; d = d0; n = (long)8192 * 1024; }
  else if (z == 1) { s = s1; d = d1; n = (long)1024 * 1024; }
  else if (z == 2) { s = s2; d = d2; n = (long)1024 * 1024; }
  else if (z == 3) { s = s3; d = d3; n = (long)1024 * 1024; }
  else             { s = s4; d = d4; n = (long)1024 * 1024; }
  const long stride = (long)512 * 256 * 16;
  for (long base = ((long)blockIdx.x * 256 + threadIdx.x) * 16; base < n;
       base += stride) {
#pragma unroll
    for (int i = 0; i < 4; ++i) {
      const float4 f = *(const float4*)(s + base + i * 4);
      u16x4 ov;
      ov.x = f2bf(f.x); ov.y = f2bf(f.y); ov.z = f2bf(f.z); ov.w = f2bf(f.w);
      *(u16x4*)(d + base + i * 4) = ov;
    }
  }
}

// ======================================================================
// GEMM pipe core (R4, best measured): C[M,N] = A[M,K] @ B[N,K]^T
// BM=128, BN=256, BK=64, 512 threads (8 waves 2Mx4N, per-wave 64x64).
// 3-region LDS round-robin (48KB/region, 144KB, 1 blk/CU). Compute tile
// t from region t%3 while staging t+2 into (t+2)%3. Boundary
// s_waitcnt vmcnt(6) lands exactly tile t+1 (counted - T4). No mid-tile
// barrier (R3 lesson: it serialized LDS reads against MFMA). Only the
// tile-boundary barrier (region recycling hazard) remains.
// R5 lesson: 256^2 geometry gave +6% per-FLOP but its 384-block grid is
// 1.5 rounds on 256 CUs -> 75% efficiency -> net -25%. This 128x256
// variant gives 768 blocks = 3 EXACT rounds for qkv and 256 = 1 exact
// round for the out-proj.
// ======================================================================
template <int MODE>
__device__ __forceinline__ void gemm_pipe_core(
    const unsigned short* __restrict__ A, const unsigned short* __restrict__ B,
    void* __restrict__ C, const float* __restrict__ bias,
    int M, int N, int K, unsigned short* __restrict__ ls) {
  const int m0 = blockIdx.x * 128;
  const int n0 = blockIdx.y * 256;
  const int tid  = threadIdx.x;
  const int lane = tid & 63;
  const int wid  = tid >> 6;
  const int quad = lane >> 4, l16 = lane & 15;
  const int wm = wid >> 2, wn = wid & 3;   // 2x4 wave grid over 128x256

  const int REG = 24576;                   // elems/region: A 8192 + B 16384

  // staging geometry: row = (tid>>3)+64q, chunk = tid&7
  // swz(row) = (row>>1)&7 = (tid>>4)&7 for all q (64q drops out of &7)
  const int srow   = tid >> 3;
  const int schunk = tid & 7;
  const int scol   = ((schunk ^ ((tid >> 4) & 7)) << 3);

  f32x4 acc[4][4];
#pragma unroll
  for (int i = 0; i < 4; ++i)
#pragma unroll
    for (int j = 0; j < 4; ++j) acc[i][j] = f32x4{0.f, 0.f, 0.f, 0.f};

  const int NT = K >> 6;

  // ---- prologue: stage tiles 0,1 into regions 0,1 (12 loads) ----
#pragma unroll
  for (int tt = 0; tt < 2; ++tt) {
    const int k0 = tt << 6;
#pragma unroll
    for (int q = 0; q < 2; ++q) {
      const int row = srow + 64 * q;
      gld_lds16(A + (size_t)(m0 + row) * K + k0 + scol,
                ls + tt * REG + row * 64 + schunk * 8);
    }
#pragma unroll
    for (int q = 0; q < 4; ++q) {
      const int row = srow + 64 * q;
      gld_lds16(B + (size_t)(n0 + row) * K + k0 + scol,
                ls + tt * REG + 8192 + row * 64 + schunk * 8);
    }
  }
  asm volatile("s_waitcnt vmcnt(6)" ::: "memory");   // tile 0 landed
  __builtin_amdgcn_s_barrier();
  __builtin_amdgcn_sched_barrier(0);

  for (int t = 0; t < NT; ++t) {
    const int rt = t % 3;
    const unsigned short* la = ls + rt * REG;
    const unsigned short* lb = la + 8192;
    const int ts = t + 2;
    const int rs = ts % 3;
    const bool doStage = ts < NT;
    const int k0s = ts << 6;
    unsigned short* da = ls + rs * REG;

    // ---------------- phase 0 (ks=0) ----------------
    {
      bf16x8 af[4], bfr[4];
#pragma unroll
      for (int mi = 0; mi < 4; ++mi)
        af[mi] = *(const bf16x8*)(la + (wm * 64 + mi * 16 + l16) * 64 +
                                  ((quad ^ (l16 >> 1)) << 3));
#pragma unroll
      for (int ni = 0; ni < 4; ++ni)
        bfr[ni] = *(const bf16x8*)(lb + (wn * 64 + ni * 16 + l16) * 64 +
                                   ((quad ^ (l16 >> 1)) << 3));
      if (doStage) {
#pragma unroll
        for (int q = 0; q < 2; ++q) {
          const int row = srow + 64 * q;
          gld_lds16(A + (size_t)(m0 + row) * K + k0s + scol,
                    da + row * 64 + schunk * 8);
        }
        gld_lds16(B + (size_t)(n0 + srow) * K + k0s + scol,
                  da + 8192 + srow * 64 + schunk * 8);
      }
      __builtin_amdgcn_s_setprio(1);
#pragma unroll
      for (int mi = 0; mi < 4; ++mi)
#pragma unroll
        for (int ni = 0; ni < 4; ++ni)
          acc[mi][ni] = __builtin_amdgcn_mfma_f32_16x16x32_bf16(
              af[mi], bfr[ni], acc[mi][ni], 0, 0, 0);
      __builtin_amdgcn_s_setprio(0);
    }
    // (no barrier: phase 1's ds_reads issue while phase 0's MFMAs run)

    // ---------------- phase 1 (ks=1) ----------------
    {
      bf16x8 af[4], bfr[4];
#pragma unroll
      for (int mi = 0; mi < 4; ++mi)
        af[mi] = *(const bf16x8*)(la + (wm * 64 + mi * 16 + l16) * 64 +
                                  (((4 + quad) ^ (l16 >> 1)) << 3));
#pragma unroll
      for (int ni = 0; ni < 4; ++ni)
        bfr[ni] = *(const bf16x8*)(lb + (wn * 64 + ni * 16 + l16) * 64 +
                                   (((4 + quad) ^ (l16 >> 1)) << 3));
      if (doStage) {
#pragma unroll
        for (int q = 1; q < 4; ++q) {
          const int row = srow + 64 * q;
          gld_lds16(B + (size_t)(n0 + row) * K + k0s + scol,
                    da + 8192 + row * 64 + schunk * 8);
        }
      }
      __builtin_amdgcn_s_setprio(1);
#pragma unroll
      for (int mi = 0; mi < 4; ++mi)
#pragma unroll
        for (int ni = 0; ni < 4; ++ni)
          acc[mi][ni] = __builtin_amdgcn_mfma_f32_16x16x32_bf16(
              af[mi], bfr[ni], acc[mi][ni], 0, 0, 0);
      __builtin_amdgcn_s_setprio(0);
    }
    // boundary: land tile t+1 before anyone reads it next iteration.
    // steady: outstanding = t+1's 6 + t+2's 6 -> vmcnt(6) lands t+1.
    // t = NT-2: nothing issued this tile -> drain NT-1's with vmcnt(0).
    if (t + 2 < NT) {
      asm volatile("s_waitcnt vmcnt(6)" ::: "memory");
    } else if (t + 1 < NT) {
      asm volatile("s_waitcnt vmcnt(0)" ::: "memory");
    }
    __builtin_amdgcn_s_barrier();
    __builtin_amdgcn_sched_barrier(0);
  }

  // epilogue: C/D layout col=lane&15, row=quad*4+reg
#pragma unroll
  for (int mi = 0; mi < 4; ++mi) {
    if (MODE == 2) {
      // transposed V write: m = token -> (b, s); n = feature -> (h, d)
      const int mB = m0 + wm * 64 + mi * 16 + quad * 4;   // r=0..3 -> s..s+3
      const int bq = mB >> 11, s = mB & 2047;
#pragma unroll
      for (int ni = 0; ni < 4; ++ni) {
        const int n = n0 + wn * 64 + ni * 16 + l16;
        u16x4 w;
        w[0] = f2bf(acc[mi][ni][0]); w[1] = f2bf(acc[mi][ni][1]);
        w[2] = f2bf(acc[mi][ni][2]); w[3] = f2bf(acc[mi][ni][3]);
        *(u16x4*)((unsigned short*)C +
                  (((size_t)((bq << 4) | (n >> 6)) * 64 + (n & 63)) << 11) + s) = w;
      }
    } else {
#pragma unroll
      for (int r = 0; r < 4; ++r) {
        const int m = m0 + wm * 64 + mi * 16 + quad * 4 + r;
#pragma unroll
        for (int ni = 0; ni < 4; ++ni) {
          const int n = n0 + wn * 64 + ni * 16 + l16;
          const float vv = acc[mi][ni][r];
          if (MODE == 0) {
            ((unsigned short*)C)[(size_t)m * N + n] = f2bf(vv);
          } else {
            ((float*)C)[(size_t)m * N + n] = vv + bias[n];
          }
        }
      }
    }
  }
}

// fused q/k/v projection; z==2 (V) writes transposed into vt[bh][d][s]
__global__ __launch_bounds__(512, 2) void gemm_qkv_kernel(
    const unsigned short* __restrict__ A,
    const unsigned short* __restrict__ B0, const unsigned short* __restrict__ B1,
    const unsigned short* __restrict__ B2,
    unsigned short* __restrict__ C0, unsigned short* __restrict__ C1,
    unsigned short* __restrict__ Cv, int M, int N, int K) {
  __shared__ unsigned short ls[3 * 24576];   // 144 KB
  if (blockIdx.z == 2) {
    gemm_pipe_core<2>(A, B2, Cv, nullptr, M, N, K, ls);
  } else {
    const unsigned short* B = blockIdx.z == 0 ? B0 : B1;
    unsigned short*       C = blockIdx.z == 0 ? C0 : C1;
    gemm_pipe_core<0>(A, B, C, nullptr, M, N, K, ls);
  }
}

// out-projection on the same pipe core: grid (64,4) = 256 blocks = exactly
// one round of 256 CUs (old 128^2 core ran 512 blocks = 2 rounds).
__global__ __launch_bounds__(512, 2) void gemm_out_kernel(
    const unsigned short* __restrict__ A, const unsigned short* __restrict__ B,
    float* __restrict__ C, const float* __restrict__ bias, int M, int N, int K) {
  __shared__ unsigned short ls[3 * 24576];   // 144 KB
  gemm_pipe_core<1>(A, B, C, bias, M, N, K, ls);
}

// ---------------- sliding-window flash attention, P-in-registers ----------
// R2 structure (T14 async-STAGE split + T5 setprio + unsigned band mask).
// R6: sigma-pack via v_cvt_pk_bf16_f32 — 16 pk-instr/jb replace ~120
// VALU/lane/jb of manual-RNE f2bf + half-insertions (attn is VALU-heavy:
// exp + pack dominate over its 32 MFMA/wave/jb).
__global__ __launch_bounds__(256) void attn_kernel(
    const unsigned short* __restrict__ q, const unsigned short* __restrict__ k,
    const unsigned short* __restrict__ vt, unsigned short* __restrict__ ctx) {
  const int bh = blockIdx.y;
  const int b = bh >> 4, h = bh & 15;
  const int i0 = blockIdx.x * 128;
  const int tid  = threadIdx.x;
  const int wave = tid >> 6, lane = tid & 63;
  const int quad = lane >> 4, l16 = lane & 15;

  __shared__ unsigned short lsQ[128 * PQ];   // [query][dim]
  __shared__ unsigned short lsK[64 * PQ];    // [key][dim]
  __shared__ unsigned short lsVp[64 * PQ];   // [dim][kslot] sigma-permuted V^T

  { // stage Q: thread pair covers one row (128B contiguous per pair)
    const int r = tid >> 1, cb = (tid & 1) * 32;
    const unsigned short* src =
        q + ((size_t)(b * S_LEN + i0 + r) * DMODEL + h * HDIM + cb);
    *(u16x8*)(lsQ + r * PQ + cb)      = *(const u16x8*)src;
    *(u16x8*)(lsQ + r * PQ + cb + 8)  = *(const u16x8*)(src + 8);
    *(u16x8*)(lsQ + r * PQ + cb + 16) = *(const u16x8*)(src + 16);
    *(u16x8*)(lsQ + r * PQ + cb + 24) = *(const u16x8*)(src + 24);
  }

  // K/V staging geometry (persistent)
  const int rr = tid >> 2, cb = (tid & 3) * 16;
  const int jhi  = cb >> 4;                          // = tid&3
  const int vbase = (jhi >> 1) * 32 + (jhi & 1) * 4; // s2*32 + jh*4

  // earliest key needed by any query in [i0, i0+127] is i0-(WIN-1)
  const int jb0 = (i0 >= WIN) ? ((i0 - WIN + 1) >> 6) : 0;
  const int jb1 = (i0 + 127) >> 6;
  const int jbi = i0 >> 6;

  // prefetch registers for next j-block's K/V (T14 async-STAGE split)
  u16x8 pk0, pk1, pv0, pv1;
  {
    const int j0 = jb0 * 64;
    const unsigned short* ks =
        k + ((size_t)(b * S_LEN + j0 + rr) * DMODEL + h * HDIM + cb);
    pk0 = *(const u16x8*)ks;
    pk1 = *(const u16x8*)(ks + 8);
    const unsigned short* vs =
        vt + ((size_t)(bh * HDIM + rr) * S_LEN + j0 + cb);
    pv0 = *(const u16x8*)vs;
    pv1 = *(const u16x8*)(vs + 8);
  }

  __syncthreads();   // lsQ ready

  // Q B-fragments in registers for the whole j-loop: q = w*32 + t*16 + l16
  bf16x8 aq[2][2];
#pragma unroll
  for (int t = 0; t < 2; ++t)
#pragma unroll
    for (int s2 = 0; s2 < 2; ++s2)
      aq[t][s2] = *(const bf16x8*)(lsQ + (wave * 32 + t * 16 + l16) * PQ +
                                   s2 * 32 + quad * 8);

  float l_lane[2] = {0.f, 0.f};   // lane-local partial softmax denominators
  f32x4 o[2][4];                  // O: [t][d-tile], row=quad*4+r=q_lo, col=l16=d_lo
#pragma unroll
  for (int t = 0; t < 2; ++t)
#pragma unroll
    for (int nd = 0; nd < 4; ++nd) o[t][nd] = f32x4{0.f, 0.f, 0.f, 0.f};

  for (int jb = jb0; jb <= jb1; ++jb) {
    const int j0 = jb * 64;
    // fully-valid blocks for ALL 128 queries: j0+63 <= i0 and i0+127-j0 < WIN
    const bool needMask = !(jb == jbi - 1 || jb == jbi - 2);
    __syncthreads();   // all waves done reading lsK/lsVp of previous jb
    { // write prefetched regs: K row-major; V^T sigma-permuted to kslots
      *(u16x8*)(lsK + rr * PQ + cb)     = pk0;
      *(u16x8*)(lsK + rr * PQ + cb + 8) = pk1;
      u16x4 w0, w1, w2, w3;
      w0[0]=pv0[0]; w0[1]=pv0[1]; w0[2]=pv0[2]; w0[3]=pv0[3];
      w1[0]=pv0[4]; w1[1]=pv0[5]; w1[2]=pv0[6]; w1[3]=pv0[7];
      w2[0]=pv1[0]; w2[1]=pv1[1]; w2[2]=pv1[2]; w2[3]=pv1[3];
      w3[0]=pv1[4]; w3[1]=pv1[5]; w3[2]=pv1[6]; w3[3]=pv1[7];
      *(u16x4*)(lsVp + rr * PQ + vbase)      = w0;   // keys m=0..3
      *(u16x4*)(lsVp + rr * PQ + vbase + 8)  = w1;   // keys m=4..7
      *(u16x4*)(lsVp + rr * PQ + vbase + 16) = w2;   // keys m=8..11
      *(u16x4*)(lsVp + rr * PQ + vbase + 24) = w3;   // keys m=12..15
    }
    __syncthreads();

    if (jb < jb1) {   // issue next tile's loads; in flight under compute
      const int jn = j0 + 64;
      const unsigned short* ks =
          k + ((size_t)(b * S_LEN + jn + rr) * DMODEL + h * HDIM + cb);
      pk0 = *(const u16x8*)ks;
      pk1 = *(const u16x8*)(ks + 8);
      const unsigned short* vs =
          vt + ((size_t)(bh * HDIM + rr) * S_LEN + jn + cb);
      pv0 = *(const u16x8*)vs;
      pv1 = *(const u16x8*)(vs + 8);
    }

    // S^T = K @ Q^T : lane holds S[q = w*32+t*16+l16][j = ni*16+quad*4+r]
    f32x4 st[2][4];
#pragma unroll
    for (int t = 0; t < 2; ++t)
#pragma unroll
      for (int ni = 0; ni < 4; ++ni) st[t][ni] = f32x4{0.f, 0.f, 0.f, 0.f};
    __builtin_amdgcn_s_setprio(1);
#pragma unroll
    for (int s2 = 0; s2 < 2; ++s2) {
      bf16x8 bk[4];
#pragma unroll
      for (int ni = 0; ni < 4; ++ni)
        bk[ni] = *(const bf16x8*)(lsK + (ni * 16 + l16) * PQ + s2 * 32 + quad * 8);
#pragma unroll
      for (int t = 0; t < 2; ++t)
#pragma unroll
        for (int ni = 0; ni < 4; ++ni)
          st[t][ni] = __builtin_amdgcn_mfma_f32_16x16x32_bf16(
              bk[ni], aq[t][s2], st[t][ni], 0, 0, 0);
    }
    __builtin_amdgcn_s_setprio(0);

    bf16x8 ap[2][2];   // PV A-frags, packed via sigma
#pragma unroll
    for (int t = 0; t < 2; ++t) {
      const int iq = i0 + wave * 32 + t * 16 + l16;
      if (needMask) {
#pragma unroll
        for (int ni = 0; ni < 4; ++ni)
#pragma unroll
          for (int r = 0; r < 4; ++r) {
            const int j = j0 + ni * 16 + quad * 4 + r;
            const bool ok = ((unsigned)(iq - j) < (unsigned)WIN);
            const float p = ok ? __expf(fminf(st[t][ni][r], 80.f)) : 0.f;
            st[t][ni][r] = p;
            l_lane[t] += p;
          }
      } else {
#pragma unroll
        for (int ni = 0; ni < 4; ++ni)
#pragma unroll
          for (int r = 0; r < 4; ++r) {
            const float p = __expf(fminf(st[t][ni][r], 80.f));
            st[t][ni][r] = p;
            l_lane[t] += p;
          }
      }
      // sigma pack via HW cvt_pk: ap elem r = st[2s2][r], elem 4+r =
      // st[2s2+1][r]; bf16x8 elems (2j,2j+1) share VGPR j -> pairs map
      // exactly to (st[ni][2c], st[ni][2c+1]).
#pragma unroll
      for (int s2 = 0; s2 < 2; ++s2) {
        union { bf16x8 v; unsigned u[4]; } a;
        a.u[0] = cvt_pk_bf16(st[t][2 * s2][0],     st[t][2 * s2][1]);
        a.u[1] = cvt_pk_bf16(st[t][2 * s2][2],     st[t][2 * s2][3]);
        a.u[2] = cvt_pk_bf16(st[t][2 * s2 + 1][0], st[t][2 * s2 + 1][1]);
        a.u[3] = cvt_pk_bf16(st[t][2 * s2 + 1][2], st[t][2 * s2 + 1][3]);
        ap[t][s2] = a.v;
      }
    }

    // O += P @ V  (B-frags shared across t)
    __builtin_amdgcn_s_setprio(1);
#pragma unroll
    for (int s2 = 0; s2 < 2; ++s2) {
      bf16x8 bv[4];
#pragma unroll
      for (int nd = 0; nd < 4; ++nd)
        bv[nd] = *(const bf16x8*)(lsVp + (nd * 16 + l16) * PQ + s2 * 32 + quad * 8);
#pragma unroll
      for (int t = 0; t < 2; ++t)
#pragma unroll
        for (int nd = 0; nd < 4; ++nd)
          o[t][nd] = __builtin_amdgcn_mfma_f32_16x16x32_bf16(
              ap[t][s2], bv[nd], o[t][nd], 0, 0, 0);
    }
    __builtin_amdgcn_s_setprio(0);
  }

  // epilogue: reduce l across quads once, then normalize + store
#pragma unroll
  for (int t = 0; t < 2; ++t) {
    float l = l_lane[t];
    l += __shfl_xor(l, 16, 64);
    l += __shfl_xor(l, 32, 64);
    const float invl = 1.f / l;
#pragma unroll
    for (int r = 0; r < 4; ++r) {
      const float inv = __shfl(invl, quad * 4 + r, 64);
      const int i = i0 + wave * 32 + t * 16 + quad * 4 + r;
#pragma unroll
      for (int nd = 0; nd < 4; ++nd)
        ctx[(size_t)(b * S_LEN + i) * DMODEL + h * HDIM + nd * 16 + l16] =
            f2bf(o[t][nd][r] * inv);
    }
  }
}

// --------------------------------------------------------------------------
extern "C" void kernel_launch(void* const* d_in, const int* in_sizes, int n_in,
                              void* d_out, int out_size, void* d_ws, size_t ws_size,
                              hipStream_t stream) {
  const float* hs = (const float*)d_in[0];
  const float* Wq = (const float*)d_in[1];
  const float* Wk = (const float*)d_in[2];
  const float* Wv = (const float*)d_in[3];
  const float* Wo = (const float*)d_in[4];
  const float* bo = (const float*)d_in[5];
  float* out = (float*)d_out;

  const size_t MD = (size_t)8192 * 1024;
  const size_t DD = (size_t)1024 * 1024;
  unsigned short* hsb  = (unsigned short*)d_ws;
  unsigned short* wqb  = hsb + MD;
  unsigned short* wkb  = wqb + DD;
  unsigned short* wvb  = wkb + DD;
  unsigned short* wob  = wvb + DD;
  unsigned short* qb   = wob + DD;
  unsigned short* kb   = qb + MD;
  unsigned short* vtb  = kb + MD;          // V^T [bh][d][s] (direct from GEMM)
  unsigned short* ctxb = vtb + MD;

  convert_kernel<<<dim3(512, 5), 256, 0, stream>>>(hs, Wq, Wk, Wv, Wo,
                                                   hsb, wqb, wkb, wvb, wob);
  gemm_qkv_kernel<<<dim3(64, 4, 3), 512, 0, stream>>>(hsb, wqb, wkb, wvb,
                                                      qb, kb, vtb, 8192, 1024, 1024);
  attn_kernel<<<dim3(16, 64), 256, 0, stream>>>(qb, kb, vtb, ctxb);
  gemm_out_kernel<<<dim3(64, 4), 512, 0, stream>>>(ctxb, wob, out, bo,
                                                   8192, 1024, 1024);
}